// Round 5
// baseline (76.844 us; speedup 1.0000x reference)
//
#include <hip/hip_runtime.h>
#include <math.h>

// B=8, N=2048, coords [B,N,3] f32. LDDT loss, upper-triangle formulation:
// both distance matrices are symmetric so num/den over {j>i} equals the
// full-matrix ratio; j>i excludes the diagonal, making the reference's
// true_d > 1e-8 test vacuous for this data.
//
// R5 structure: NO LDS, NO barriers. The j-side point data is wave-uniform
// (uniform loop index + blockIdx-derived base), so it is read through the
// scalar pipe (SMEM s_load) directly from global/L2 — deleting the staging
// phase and both ds_read_b128 per iter. Diagonal-tile j>i test is a SALU
// prefix mask instead of a ballot. Each wave stores its own float2 partial
// (ballot counters are wave-uniform) — no cross-wave reduction.
constexpr int B  = 8;
constexpr int N  = 2048;
constexpr int TI = 256;        // i-points per block == threads (4 waves)
constexpr int TJ = 64;         // j-points per tile
constexpr int TILES = 144;     // per batch: c >= 4a, a in [0,8), c in [0,32)
constexpr int WPB = TI / 64;   // waves per block

template <bool CHECK>
__device__ __forceinline__ void inner_loop(
    const float* __restrict__ pj,    // pred j-base  (wave-uniform)
    const float* __restrict__ tj,    // true j-base  (wave-uniform)
    float pix, float piy, float piz,
    float tix, float tiy, float tiz,
    int k0,                          // j0-i0w (uniform, CHECK tiles only)
    unsigned& c0, unsigned& c1, unsigned& c2, unsigned& c3, unsigned& cd)
{
    #pragma unroll 4
    for (int j = 0; j < TJ; ++j) {
        // uniform addresses -> scalar loads (SMEM), no VALU/LDS cost
        float pjx = pj[3 * j + 0], pjy = pj[3 * j + 1], pjz = pj[3 * j + 2];
        float tjx = tj[3 * j + 0], tjy = tj[3 * j + 1], tjz = tj[3 * j + 2];

        float dx = pix - pjx, dy = piy - pjy, dz = piz - pjz;
        float pd2 = fmaf(dx, dx, fmaf(dy, dy, dz * dz));
        float ex = tix - tjx, ey = tiy - tjy, ez = tiz - tjz;
        float td2 = fmaf(ex, ex, fmaf(ey, ey, ez * ez));

        // local mask (squared domain): true_d < 15
        unsigned long long m = __ballot(td2 < 225.0f);
        if (CHECK) {
            // lane l allowed iff (j0+j) > (i0 + 64*wave + l)  <=>  l < k0 + j
            int kw = k0 + j;   // uniform -> SALU prefix mask
            unsigned long long mji =
                (kw >= 64) ? ~0ull : ((kw <= 0) ? 0ull : ((1ull << kw) - 1ull));
            m &= mji;
        }

        float diff = fabsf(__builtin_amdgcn_sqrtf(pd2) - __builtin_amdgcn_sqrtf(td2));

        // cumulative bins: score = .5*[d<.5] + .25*[d<1] + .125*[d<2] + .125*[d<4]
        c0 += __popcll(m & __ballot(diff < 0.5f));
        c1 += __popcll(m & __ballot(diff < 1.0f));
        c2 += __popcll(m & __ballot(diff < 2.0f));
        c3 += __popcll(m & __ballot(diff < 4.0f));
        cd += __popcll(m);
    }
}

__global__ __launch_bounds__(TI) void lddt_partial(
    const float* __restrict__ pred,   // [B,N,3]
    const float* __restrict__ truec,  // [B,N,3]
    float2* __restrict__ part)        // [B, TILES*WPB]
{
    const int b = blockIdx.y;
    // decode linear tile index -> (a = i-tile, c = j-tile), c in [4a, 32)
    int r = blockIdx.x, a = 0;
    while (r >= 32 - 4 * a) { r -= 32 - 4 * a; ++a; }
    const int c = 4 * a + r;
    const int i0 = a * TI;
    const int j0 = c * TJ;
    const int t = threadIdx.x;
    const int wave = t >> 6;

    const int i = i0 + t;
    const float* pi = pred  + ((size_t)b * N + i) * 3;
    const float* ti = truec + ((size_t)b * N + i) * 3;
    const float pix = pi[0], piy = pi[1], piz = pi[2];
    const float tix = ti[0], tiy = ti[1], tiz = ti[2];

    const float* pj = pred  + ((size_t)b * N + j0) * 3;
    const float* tj = truec + ((size_t)b * N + j0) * 3;

    unsigned c0 = 0, c1 = 0, c2 = 0, c3 = 0, cd = 0;

    if (c >= 4 * a + 4) {   // off-diagonal tile: all j > i guaranteed
        inner_loop<false>(pj, tj, pix, piy, piz, tix, tiy, tiz, 0,
                          c0, c1, c2, c3, cd);
    } else {                // diagonal-band tile: SALU prefix-mask j>i
        const int k0 = j0 - (i0 + 64 * wave);
        inner_loop<true>(pj, tj, pix, piy, piz, tix, tiy, tiz, k0,
                         c0, c1, c2, c3, cd);
    }

    // ballot counters are wave-uniform: lane 0 of each wave stores its slot
    if ((t & 63) == 0) {
        float n = 0.5f * (float)c0 + 0.25f * (float)c1
                + 0.125f * (float)c2 + 0.125f * (float)c3;
        part[(size_t)b * (TILES * WPB) + blockIdx.x * WPB + wave] =
            make_float2(n, (float)cd);
    }
}

// 512 threads = 8 waves; wave w reduces batch w's TILES*WPB slots.
__global__ __launch_bounds__(512) void lddt_reduce(
    const float2* __restrict__ part,  // [B, TILES*WPB]
    float* __restrict__ out)          // [1]
{
    constexpr int SLOTS = TILES * WPB;   // 576
    const int t = threadIdx.x;
    const int w = t >> 6;     // batch
    const int l = t & 63;

    float n = 0.0f, d = 0.0f;
    for (int s = l; s < SLOTS; s += 64) {
        float2 v = part[(size_t)w * SLOTS + s];
        n += v.x;
        d += v.y;
    }
    for (int off = 32; off > 0; off >>= 1) {
        n += __shfl_down(n, off, 64);
        d += __shfl_down(d, off, 64);
    }

    __shared__ float acc[B];
    if (l == 0) acc[w] = 1.0f - n / fmaxf(d, 1e-8f);
    __syncthreads();

    if (t == 0) {
        float s = 0.0f;
        #pragma unroll
        for (int b = 0; b < B; ++b) s += acc[b];
        out[0] = s / (float)B;
    }
}

extern "C" void kernel_launch(void* const* d_in, const int* in_sizes, int n_in,
                              void* d_out, int out_size, void* d_ws, size_t ws_size,
                              hipStream_t stream)
{
    const float* pred  = (const float*)d_in[0];
    const float* truec = (const float*)d_in[1];
    float* out   = (float*)d_out;
    float2* part = (float2*)d_ws;   // B * TILES * WPB float2 = 36 KB

    dim3 grid(TILES, B);
    lddt_partial<<<grid, TI, 0, stream>>>(pred, truec, part);
    lddt_reduce<<<1, 512, 0, stream>>>(part, out);
}